// Round 1
// baseline (169.569 us; speedup 1.0000x reference)
//
#include <hip/hip_runtime.h>
#include <math.h>
#include <stdint.h>

// Problem constants (match reference)
constexpr int kVerts = 5000;
constexpr int kFaces = 10000;
constexpr int kHalf  = kFaces / 2;
constexpr int kPts   = 16384;   // BATCH * N_PTS = 2 * 8192
constexpr int kOuter = 4;
constexpr int kInner = 50;

#define SCALE 10.0f

// ---------------------------------------------------------------------------
// Compile-time Adam bias-correction tables. With the inner loop FULLY
// unrolled these fold to inline literals.
// ---------------------------------------------------------------------------
struct BiasTab { float rb1[kInner]; float rb2[kInner]; };
constexpr BiasTab make_tab() {
    BiasTab t{};
    float b1 = 1.0f, b2 = 1.0f;
    for (int i = 0; i < kInner; ++i) {
        b1 *= 0.9f; b2 *= 0.999f;
        t.rb1[i] = 1.0f / (1.0f - b1);
        t.rb2[i] = 1.0f / (1.0f - b2);
    }
    return t;
}
constexpr BiasTab kTab = make_tab();

// ---------------------------------------------------------------------------
// Kernel 0: precompute triangle centers once (bit-identical *_rn formula).
// cent[f] = (cx, cy, cz, cc = |c|^2)
// ---------------------------------------------------------------------------
__global__ __launch_bounds__(256)
void centers_kernel(const float* __restrict__ mesh_V,
                    const int*   __restrict__ mesh_F,
                    float4*      __restrict__ cent)
{
    const int f = blockIdx.x * 256 + threadIdx.x;
    if (f >= kFaces) return;
    const int i0 = mesh_F[f * 3 + 0];
    const int i1 = mesh_F[f * 3 + 1];
    const int i2 = mesh_F[f * 3 + 2];
    const float cx = __fdiv_rn(__fadd_rn(__fadd_rn(mesh_V[i0*3+0], mesh_V[i1*3+0]), mesh_V[i2*3+0]), 3.0f);
    const float cy = __fdiv_rn(__fadd_rn(__fadd_rn(mesh_V[i0*3+1], mesh_V[i1*3+1]), mesh_V[i2*3+1]), 3.0f);
    const float cz = __fdiv_rn(__fadd_rn(__fadd_rn(mesh_V[i0*3+2], mesh_V[i1*3+2]), mesh_V[i2*3+2]), 3.0f);
    const float cc = __fadd_rn(__fadd_rn(__fmul_rn(cx, cx), __fmul_rn(cy, cy)),
                               __fmul_rn(cz, cz));
    cent[f] = make_float4(cx, cy, cz, cc);
}

// ---------------------------------------------------------------------------
// Kernel 1: KNN (K=1).
// Round-5 counters: VGPR=20/SGPR=64 -> centroid stream was SCALAR loads.
// SMEM returns out-of-order => every batch needs lgkmcnt(0) before ANY use:
// no partial-wait pipelining, and 64-SGPR budget caps batch depth. VALUBusy
// stuck at 54% (VALU floor ~23us vs measured 49us).
// Change: launder the centroid base pointer into a VGPR (empty asm) so the
// compiler emits global_load_dwordx4 (in-order return, staged vmcnt waits,
// one coalesced 16B request per uniform-address load). 8 float4 in flight
// = 32 data VGPRs; total stays <=64 VGPR so 2 blocks/CU (8 waves/SIMD) is
// preserved. Distance arithmetic UNCHANGED (bit-identical argmin).
// ---------------------------------------------------------------------------
#define KNN_PARTS 16

__global__ __launch_bounds__(1024)
void knn_kernel(const float* __restrict__ verts,
                const float4* __restrict__ cent,
                float*        __restrict__ ws_d2,   // [2][kPts]
                int*          __restrict__ ws_f)    // [2][kPts]
{
    __shared__ float s_best[1024];
    __shared__ int   s_bestf[1024];

    const int tid  = threadIdx.x;
    const int lane = tid & 63;
    const int part = __builtin_amdgcn_readfirstlane(tid >> 6);   // 0..15
    const int pg   = blockIdx.x >> 1;
    const int half = blockIdx.x & 1;
    const int p    = pg * 64 + lane;

    const float qx = verts[p * 3 + 0];
    const float qy = verts[p * 3 + 1];
    const float qz = verts[p * 3 + 2];
    // (verts**2).sum(-1): (x^2 + y^2) + z^2, plain ops
    const float q2 = __fadd_rn(__fadd_rn(__fmul_rn(qx, qx), __fmul_rn(qy, qy)),
                               __fmul_rn(qz, qz));

    // this wave's contiguous face range within its half
    const int fbeg = half * kHalf + (part * kHalf) / KNN_PARTS;
    const int fend = half * kHalf + ((part + 1) * kHalf) / KNN_PARTS;

    // Launder the base pointer through an empty asm so the address lives in
    // VGPRs -> compiler must use VMEM (global_load_dwordx4) instead of SMEM.
    // All lanes hold the same value: each load coalesces to ONE 16B request.
    uintptr_t cb = (uintptr_t)cent;
    asm("" : "+v"(cb));
    const float4* __restrict__ vcent = (const float4*)cb;

    // 4 independent accumulators to break the compare dependency chain
    float bd0 = INFINITY, bd1 = INFINITY, bd2 = INFINITY, bd3 = INFINITY;
    int   bf0 = 0x7fffffff, bf1 = 0x7fffffff, bf2 = 0x7fffffff, bf3 = 0x7fffffff;

#define KNN_EVAL(FF, C, BD, BF)                                                       \
    {                                                                                 \
        const float dot = __fadd_rn(__fadd_rn(__fmul_rn(qx, (C).x),                   \
                                              __fmul_rn(qy, (C).y)),                  \
                                    __fmul_rn(qz, (C).z));                            \
        const float d2 = __fsub_rn(__fadd_rn(q2, (C).w), __fmul_rn(2.0f, dot));       \
        if (d2 < (BD)) { (BD) = d2; (BF) = (FF); }                                    \
    }

    int f = fbeg;
    // 8 loads in flight per iteration; unroll 1 keeps VGPR <= 64 so the
    // 2-blocks/CU occupancy (8 waves/SIMD) survives.
#pragma unroll 1
    for (; f + 8 <= fend; f += 8) {
        const float4 c0 = vcent[f + 0];
        const float4 c1 = vcent[f + 1];
        const float4 c2 = vcent[f + 2];
        const float4 c3 = vcent[f + 3];
        const float4 c4 = vcent[f + 4];
        const float4 c5 = vcent[f + 5];
        const float4 c6 = vcent[f + 6];
        const float4 c7 = vcent[f + 7];
        KNN_EVAL(f + 0, c0, bd0, bf0);
        KNN_EVAL(f + 1, c1, bd1, bf1);
        KNN_EVAL(f + 2, c2, bd2, bf2);
        KNN_EVAL(f + 3, c3, bd3, bf3);
        KNN_EVAL(f + 4, c4, bd0, bf0);
        KNN_EVAL(f + 5, c5, bd1, bf1);
        KNN_EVAL(f + 6, c6, bd2, bf2);
        KNN_EVAL(f + 7, c7, bd3, bf3);
    }
    for (; f < fend; ++f) {
        const float4 c0 = vcent[f];
        KNN_EVAL(f, c0, bd0, bf0);   // tail faces exceed all prior bf0 faces
    }
#undef KNN_EVAL

    // lexicographic merge of the 4 accumulators (smaller f wins ties)
    if (bd1 < bd0 || (bd1 == bd0 && bf1 < bf0)) { bd0 = bd1; bf0 = bf1; }
    if (bd3 < bd2 || (bd3 == bd2 && bf3 < bf2)) { bd2 = bd3; bf2 = bf3; }
    if (bd2 < bd0 || (bd2 == bd0 && bf2 < bf0)) { bd0 = bd2; bf0 = bf2; }

    s_best[tid]  = bd0;
    s_bestf[tid] = bf0;
    __syncthreads();
    if (part == 0) {
        float best  = bd0;
        int   bestf = bf0;
        for (int k = 1; k < KNN_PARTS; ++k) {
            const float ob = s_best[tid + 64 * k];
            const int   of = s_bestf[tid + 64 * k];
            if (ob < best || (ob == best && of < bestf)) { best = ob; bestf = of; }
        }
        ws_d2[half * kPts + p] = best;
        ws_f [half * kPts + p] = bestf;
    }
}

// ---------------------------------------------------------------------------
// Kernel 2: solve — SAME MATH as previous rounds (absmax frozen).
// ---------------------------------------------------------------------------
__global__ __launch_bounds__(64)
void solve_kernel(const float* __restrict__ verts,
                  const float* __restrict__ mesh_V,
                  const float* __restrict__ mesh_N,
                  const int*   __restrict__ mesh_F,
                  const float* __restrict__ ws_d2,
                  const int*   __restrict__ ws_f,
                  float*       __restrict__ out)
{
    const int p = blockIdx.x * 64 + threadIdx.x;

    // merge halves: half 0 wins ties (lower indices) == first occurrence
    const float da = ws_d2[p];
    const float db = ws_d2[kPts + p];
    const int   fa = ws_f[p];
    const int   fb = ws_f[kPts + p];
    const int   f  = (db < da) ? fb : fa;
    out[p] = (float)f;   // fidx as float (exact for idx < 2^24)

    const float qx = verts[p * 3 + 0];
    const float qy = verts[p * 3 + 1];
    const float qz = verts[p * 3 + 2];

    const int i0 = mesh_F[f * 3 + 0];
    const int i1 = mesh_F[f * 3 + 1];
    const int i2 = mesh_F[f * 3 + 2];

    const float V0x = mesh_V[i0*3+0], V0y = mesh_V[i0*3+1], V0z = mesh_V[i0*3+2];
    const float V1x = mesh_V[i1*3+0], V1y = mesh_V[i1*3+1], V1z = mesh_V[i1*3+2];
    const float V2x = mesh_V[i2*3+0], V2y = mesh_V[i2*3+1], V2z = mesh_V[i2*3+2];
    const float N0x = mesh_N[i0*3+0], N0y = mesh_N[i0*3+1], N0z = mesh_N[i0*3+2];
    const float N1x = mesh_N[i1*3+0], N1y = mesh_N[i1*3+1], N1z = mesh_N[i1*3+2];
    const float N2x = mesh_N[i2*3+0], N2y = mesh_N[i2*3+1], N2z = mesh_N[i2*3+2];

    // edge vectors for gradient dots
    const float E0x = V0x - V2x, E0y = V0y - V2y, E0z = V0z - V2z;
    const float E1x = V1x - V2x, E1y = V1y - V2y, E1z = V1z - V2z;
    const float F0x = N0x - N2x, F0y = N0y - N2y, F0z = N0z - N2z;
    const float F1x = N1x - N2x, F1y = N1y - N2y, F1z = N1z - N2z;

    const float tx = qx * SCALE, ty = qy * SCALE, tz = qz * SCALE;
    const float GS = 2.0f / (3.0f * 16384.0f);
    const float B1 = 0.9f,  ONE_M_B1 = 1.0f - 0.9f;
    const float B2 = 0.999f, ONE_M_B2 = 1.0f - 0.999f;

    float vwu = 1.0f / 3.0f, vwv = 1.0f / 3.0f;

    for (int outer = 0; outer < kOuter; ++outer) {
        const float bw0 = (1.0f - vwu) - vwv;
        const float px = ((vwu * V0x + vwv * V1x) + bw0 * V2x);
        const float py = ((vwu * V0y + vwv * V1y) + bw0 * V2y);
        const float pz = ((vwu * V0z + vwv * V1z) + bw0 * V2z);
        const float dx = px - qx, dy = py - qy, dz = pz - qz;
        const float d0 = __builtin_amdgcn_sqrtf((dx * dx + dy * dy) + dz * dz);

        float du = 0.0f, dv = 0.0f, dd = d0;
        float mAu = 0.0f, mAv = 0.0f, mAd = 0.0f;
        float vAu = 0.0f, vAv = 0.0f, vAd = 0.0f;

#pragma unroll
        for (int it = 0; it < kInner; ++it) {
            const float bu = vwu + du;
            const float bv = vwv + dv;
            const float bw = (1.0f - bu) - bv;

            const float cVx = ((bu * V0x + bv * V1x) + bw * V2x) * SCALE;
            const float cVy = ((bu * V0y + bv * V1y) + bw * V2y) * SCALE;
            const float cVz = ((bu * V0z + bv * V1z) + bw * V2z) * SCALE;

            const float nrx = (bu * N0x + bv * N1x) + bw * N2x;
            const float nry = (bu * N0y + bv * N1y) + bw * N2y;
            const float nrz = (bu * N0z + bv * N1z) + bw * N2z;
            const float nn  = (nrx * nrx + nry * nry) + nrz * nrz;
            // 1/max(sqrt(nn),1e-12) == rsq(nn) for the magnitudes here
            const float inv = __builtin_amdgcn_rsqf(nn);
            const float nhx = nrx * inv, nhy = nry * inv, nhz = nrz * inv;
            const float cNx = nhx * SCALE, cNy = nhy * SCALE, cNz = nhz * SCALE;

            const float rx = (cVx + cNx * dd) - tx;
            const float ry = (cVy + cNy * dd) - ty;
            const float rz = (cVz + cNz * dd) - tz;

            const float rv0  = (rx * E0x + ry * E0y) + rz * E0z;
            const float rv1  = (rx * E1x + ry * E1y) + rz * E1z;
            const float rn0  = (rx * F0x + ry * F0y) + rz * F0z;
            const float rn1  = (rx * F1x + ry * F1y) + rz * F1z;
            const float nf0  = (nhx * F0x + nhy * F0y) + nhz * F0z;
            const float nf1  = (nhx * F1x + nhy * F1y) + nhz * F1z;
            const float nr_r = (nhx * rx + nhy * ry) + nhz * rz;

            const float gu = GS * (SCALE * rv0 + (dd * SCALE) * ((rn0 - nr_r * nf0) * inv));
            const float gv = GS * (SCALE * rv1 + (dd * SCALE) * ((rn1 - nr_r * nf1) * inv));
            const float gd = GS * (SCALE * nr_r);

            mAu = B1 * mAu + ONE_M_B1 * gu;
            mAv = B1 * mAv + ONE_M_B1 * gv;
            mAd = B1 * mAd + ONE_M_B1 * gd;
            vAu = B2 * vAu + ONE_M_B2 * (gu * gu);
            vAv = B2 * vAv + ONE_M_B2 * (gv * gv);
            vAd = B2 * vAd + ONE_M_B2 * (gd * gd);

            const float rb1 = kTab.rb1[it];   // compile-time literal (full unroll)
            const float rb2 = kTab.rb2[it];
            // mhat/(sqrt(vhat)+1e-8) ~= mhat * rsq(vhat + 1e-16)
            const float su = __builtin_amdgcn_rsqf(vAu * rb2 + 1e-16f);
            const float sv = __builtin_amdgcn_rsqf(vAv * rb2 + 1e-16f);
            const float sd = __builtin_amdgcn_rsqf(vAd * rb2 + 1e-16f);
            du -= 0.01f * (mAu * rb1) * su;
            dv -= 0.01f * (mAv * rb1) * sv;
            dd -= 0.01f * (mAd * rb1) * sd;
        }
        vwu += du;
        vwv += dv;
    }

    out[kPts + 2 * p + 0] = vwu;
    out[kPts + 2 * p + 1] = vwv;
    out[3 * kPts + p]     = 0.0f;   // outlier_mask = False
}

extern "C" void kernel_launch(void* const* d_in, const int* in_sizes, int n_in,
                              void* d_out, int out_size, void* d_ws, size_t ws_size,
                              hipStream_t stream) {
    const float* verts  = (const float*)d_in[0];
    const float* mesh_V = (const float*)d_in[1];
    const float* mesh_N = (const float*)d_in[2];
    const int*   mesh_F = (const int*)d_in[3];
    float* out = (float*)d_out;

    // workspace layout: centers | d2 candidates | face candidates
    float4* ws_cent = (float4*)d_ws;                                   // kFaces float4
    float*  ws_d2   = (float*)((char*)d_ws + kFaces * sizeof(float4)); // [2][kPts]
    int*    ws_f    = (int*)((char*)ws_d2 + 2 * kPts * sizeof(float)); // [2][kPts]

    hipLaunchKernelGGL(centers_kernel, dim3((kFaces + 255) / 256), dim3(256), 0, stream,
                       mesh_V, mesh_F, ws_cent);
    hipLaunchKernelGGL(knn_kernel,     dim3(2 * kPts / 64), dim3(1024), 0, stream,
                       verts, ws_cent, ws_d2, ws_f);
    hipLaunchKernelGGL(solve_kernel,   dim3(kPts / 64), dim3(64), 0, stream,
                       verts, mesh_V, mesh_N, mesh_F, ws_d2, ws_f, out);
}

// Round 2
// 145.497 us; speedup vs baseline: 1.1654x; 1.1654x over previous
//
#include <hip/hip_runtime.h>
#include <math.h>
#include <stdint.h>

// Problem constants (match reference)
constexpr int kVerts = 5000;
constexpr int kFaces = 10000;
constexpr int kPts   = 16384;   // BATCH * N_PTS = 2 * 8192
constexpr int kOuter = 4;
constexpr int kInner = 50;

#define SCALE 10.0f

// KNN structure: 4 points per lane, 16 waves per block, 4 cross-block face
// quarters. Block = 256 points x 2500 faces; wave = 256 points x ~156 faces.
#define KNN_WAVES 16
#define KNN_FQ    4
constexpr int kQuarter     = kFaces / KNN_FQ;        // 2500
constexpr int kPtsPerLane  = 4;
constexpr int kPtsPerBlock = 64 * kPtsPerLane;       // 256
constexpr int kPtGroups    = kPts / kPtsPerBlock;    // 64

// ---------------------------------------------------------------------------
// Compile-time Adam bias-correction tables (fold to literals under full
// unroll in solve_kernel).
// ---------------------------------------------------------------------------
struct BiasTab { float rb1[kInner]; float rb2[kInner]; };
constexpr BiasTab make_tab() {
    BiasTab t{};
    float b1 = 1.0f, b2 = 1.0f;
    for (int i = 0; i < kInner; ++i) {
        b1 *= 0.9f; b2 *= 0.999f;
        t.rb1[i] = 1.0f / (1.0f - b1);
        t.rb2[i] = 1.0f / (1.0f - b2);
    }
    return t;
}
constexpr BiasTab kTab = make_tab();

// ---------------------------------------------------------------------------
// Kernel 0: precompute triangle centers once (bit-identical *_rn formula).
// cent[f] = (cx, cy, cz, cc = |c|^2)
// ---------------------------------------------------------------------------
__global__ __launch_bounds__(256)
void centers_kernel(const float* __restrict__ mesh_V,
                    const int*   __restrict__ mesh_F,
                    float4*      __restrict__ cent)
{
    const int f = blockIdx.x * 256 + threadIdx.x;
    if (f >= kFaces) return;
    const int i0 = mesh_F[f * 3 + 0];
    const int i1 = mesh_F[f * 3 + 1];
    const int i2 = mesh_F[f * 3 + 2];
    const float cx = __fdiv_rn(__fadd_rn(__fadd_rn(mesh_V[i0*3+0], mesh_V[i1*3+0]), mesh_V[i2*3+0]), 3.0f);
    const float cy = __fdiv_rn(__fadd_rn(__fadd_rn(mesh_V[i0*3+1], mesh_V[i1*3+1]), mesh_V[i2*3+1]), 3.0f);
    const float cz = __fdiv_rn(__fadd_rn(__fadd_rn(mesh_V[i0*3+2], mesh_V[i1*3+2]), mesh_V[i2*3+2]), 3.0f);
    const float cc = __fadd_rn(__fadd_rn(__fmul_rn(cx, cx), __fmul_rn(cy, cy)),
                               __fmul_rn(cz, cz));
    cent[f] = make_float4(cx, cy, cz, cc);
}

// ---------------------------------------------------------------------------
// Kernel 1: KNN (K=1).
// Round-6 post-mortem: VMEM uniform-address loads broadcast 16B -> ALL 64
// lanes (1KB of L1-return per load) => return-BW-bound (83us, matches
// 10000 loads/CU x ~16cyc). SMEM was right (16B once per wave); its only
// cost was lgkmcnt(0) per batch at 88-cyc compute granularity (54% busy).
// Fix: 4 points per lane => per 8-face scalar batch the compute is
// 8 faces x 4 pts x 10 ops = 320 wave-insts (~640 cyc) against ONE
// lgkmcnt wait; 4 waves/SIMD cover the rest. Also pre-double the query
// (2qx,2qy,2qz): x2 commutes exactly with rn-rounding, so
// dot2 == fmul_rn(2,dot) bit-exactly -> d2 bits unchanged, 1 op saved.
// Merge order: strict < over ascending face ranges (acc-pair lexicographic)
// == first-occurrence argmin, identical fidx to previous rounds.
// ---------------------------------------------------------------------------
__global__ __launch_bounds__(1024)
void knn_kernel(const float* __restrict__ verts,
                const float4* __restrict__ cent,
                float*        __restrict__ ws_d2,   // [KNN_FQ][kPts]
                int*          __restrict__ ws_f)    // [KNN_FQ][kPts]
{
    __shared__ float s_best [KNN_WAVES * kPtsPerBlock];   // 16 KB
    __shared__ int   s_bestf[KNN_WAVES * kPtsPerBlock];   // 16 KB

    const int tid  = threadIdx.x;
    const int lane = tid & 63;
    const int wv   = __builtin_amdgcn_readfirstlane(tid >> 6);   // 0..15
    const int pg   = blockIdx.x >> 2;   // point group 0..63
    const int fq   = blockIdx.x & 3;    // face quarter 0..3

    // Load this lane's 4 points; store doubled coords (exact) + |q|^2.
    float dqx[kPtsPerLane], dqy[kPtsPerLane], dqz[kPtsPerLane], q2[kPtsPerLane];
#pragma unroll
    for (int k = 0; k < kPtsPerLane; ++k) {
        const int p = pg * kPtsPerBlock + k * 64 + lane;
        const float qx = verts[p * 3 + 0];
        const float qy = verts[p * 3 + 1];
        const float qz = verts[p * 3 + 2];
        q2[k] = __fadd_rn(__fadd_rn(__fmul_rn(qx, qx), __fmul_rn(qy, qy)),
                          __fmul_rn(qz, qz));
        dqx[k] = __fmul_rn(2.0f, qx);
        dqy[k] = __fmul_rn(2.0f, qy);
        dqz[k] = __fmul_rn(2.0f, qz);
    }

    // this wave's contiguous face slice within its quarter (ascending in wv)
    const int qbeg = fq * kQuarter;
    const int fbeg = qbeg + (wv * kQuarter) / KNN_WAVES;
    const int fend = qbeg + ((wv + 1) * kQuarter) / KNN_WAVES;

    // 2 accumulators per point to break the cmp/cndmask dependency chain
    float bd[kPtsPerLane][2];
    int   bf[kPtsPerLane][2];
#pragma unroll
    for (int k = 0; k < kPtsPerLane; ++k) {
        bd[k][0] = INFINITY; bd[k][1] = INFINITY;
        bf[k][0] = 0x7fffffff; bf[k][1] = 0x7fffffff;
    }

    // d2 = (q2 + |c|^2) - (2qx*cx + 2qy*cy + 2qz*cz)   [bit-identical]
#define KNN_EVAL(FF, C, K, A)                                                         \
    {                                                                                 \
        const float dot2 = __fadd_rn(__fadd_rn(__fmul_rn(dqx[K], (C).x),              \
                                               __fmul_rn(dqy[K], (C).y)),             \
                                     __fmul_rn(dqz[K], (C).z));                       \
        const float d2 = __fsub_rn(__fadd_rn(q2[K], (C).w), dot2);                    \
        if (d2 < bd[K][A]) { bd[K][A] = d2; bf[K][A] = (FF); }                        \
    }

    int f = fbeg;
#pragma unroll 1
    for (; f + 8 <= fend; f += 8) {
        // wave-uniform addresses -> scalar (SMEM) loads, 16B once per wave
        const float4 c0 = cent[f + 0];
        const float4 c1 = cent[f + 1];
        const float4 c2 = cent[f + 2];
        const float4 c3 = cent[f + 3];
        const float4 c4 = cent[f + 4];
        const float4 c5 = cent[f + 5];
        const float4 c6 = cent[f + 6];
        const float4 c7 = cent[f + 7];
#pragma unroll
        for (int k = 0; k < kPtsPerLane; ++k) {
            KNN_EVAL(f + 0, c0, k, 0);
            KNN_EVAL(f + 1, c1, k, 1);
            KNN_EVAL(f + 2, c2, k, 0);
            KNN_EVAL(f + 3, c3, k, 1);
            KNN_EVAL(f + 4, c4, k, 0);
            KNN_EVAL(f + 5, c5, k, 1);
            KNN_EVAL(f + 6, c6, k, 0);
            KNN_EVAL(f + 7, c7, k, 1);
        }
    }
    for (; f < fend; ++f) {
        const float4 c0 = cent[f];
#pragma unroll
        for (int k = 0; k < kPtsPerLane; ++k)
            KNN_EVAL(f, c0, k, 0);    // tail faces exceed all acc0 faces
    }
#undef KNN_EVAL

    // per-point lexicographic merge of the 2 accumulators (smaller f on ties)
#pragma unroll
    for (int k = 0; k < kPtsPerLane; ++k) {
        if (bd[k][1] < bd[k][0] || (bd[k][1] == bd[k][0] && bf[k][1] < bf[k][0])) {
            bd[k][0] = bd[k][1]; bf[k][0] = bf[k][1];
        }
        s_best [wv * kPtsPerBlock + k * 64 + lane] = bd[k][0];
        s_bestf[wv * kPtsPerBlock + k * 64 + lane] = bf[k][0];
    }
    __syncthreads();

    // cross-wave merge: wave w's face range is strictly below wave w+1's,
    // so strict < keeps the smaller face index on exact ties.
    if (tid < kPtsPerBlock) {
        float best  = s_best[tid];
        int   bestf = s_bestf[tid];
#pragma unroll
        for (int w = 1; w < KNN_WAVES; ++w) {
            const float ob = s_best [w * kPtsPerBlock + tid];
            const int   of = s_bestf[w * kPtsPerBlock + tid];
            if (ob < best) { best = ob; bestf = of; }
        }
        const int p = pg * kPtsPerBlock + tid;
        ws_d2[fq * kPts + p] = best;
        ws_f [fq * kPts + p] = bestf;
    }
}

// ---------------------------------------------------------------------------
// Kernel 2: solve — SAME MATH as previous rounds (absmax frozen). Only the
// candidate merge changed: 4 quarters instead of 2 halves (strict < keeps
// the earlier quarter = smaller face index on exact ties).
// ---------------------------------------------------------------------------
__global__ __launch_bounds__(64)
void solve_kernel(const float* __restrict__ verts,
                  const float* __restrict__ mesh_V,
                  const float* __restrict__ mesh_N,
                  const int*   __restrict__ mesh_F,
                  const float* __restrict__ ws_d2,
                  const int*   __restrict__ ws_f,
                  float*       __restrict__ out)
{
    const int p = blockIdx.x * 64 + threadIdx.x;

    float bdm = ws_d2[p];
    int   f   = ws_f[p];
#pragma unroll
    for (int q = 1; q < KNN_FQ; ++q) {
        const float d  = ws_d2[q * kPts + p];
        const int   ff = ws_f [q * kPts + p];
        if (d < bdm) { bdm = d; f = ff; }
    }
    out[p] = (float)f;   // fidx as float (exact for idx < 2^24)

    const float qx = verts[p * 3 + 0];
    const float qy = verts[p * 3 + 1];
    const float qz = verts[p * 3 + 2];

    const int i0 = mesh_F[f * 3 + 0];
    const int i1 = mesh_F[f * 3 + 1];
    const int i2 = mesh_F[f * 3 + 2];

    const float V0x = mesh_V[i0*3+0], V0y = mesh_V[i0*3+1], V0z = mesh_V[i0*3+2];
    const float V1x = mesh_V[i1*3+0], V1y = mesh_V[i1*3+1], V1z = mesh_V[i1*3+2];
    const float V2x = mesh_V[i2*3+0], V2y = mesh_V[i2*3+1], V2z = mesh_V[i2*3+2];
    const float N0x = mesh_N[i0*3+0], N0y = mesh_N[i0*3+1], N0z = mesh_N[i0*3+2];
    const float N1x = mesh_N[i1*3+0], N1y = mesh_N[i1*3+1], N1z = mesh_N[i1*3+2];
    const float N2x = mesh_N[i2*3+0], N2y = mesh_N[i2*3+1], N2z = mesh_N[i2*3+2];

    // edge vectors for gradient dots
    const float E0x = V0x - V2x, E0y = V0y - V2y, E0z = V0z - V2z;
    const float E1x = V1x - V2x, E1y = V1y - V2y, E1z = V1z - V2z;
    const float F0x = N0x - N2x, F0y = N0y - N2y, F0z = N0z - N2z;
    const float F1x = N1x - N2x, F1y = N1y - N2y, F1z = N1z - N2z;

    const float tx = qx * SCALE, ty = qy * SCALE, tz = qz * SCALE;
    const float GS = 2.0f / (3.0f * 16384.0f);
    const float B1 = 0.9f,  ONE_M_B1 = 1.0f - 0.9f;
    const float B2 = 0.999f, ONE_M_B2 = 1.0f - 0.999f;

    float vwu = 1.0f / 3.0f, vwv = 1.0f / 3.0f;

    for (int outer = 0; outer < kOuter; ++outer) {
        const float bw0 = (1.0f - vwu) - vwv;
        const float px = ((vwu * V0x + vwv * V1x) + bw0 * V2x);
        const float py = ((vwu * V0y + vwv * V1y) + bw0 * V2y);
        const float pz = ((vwu * V0z + vwv * V1z) + bw0 * V2z);
        const float dx = px - qx, dy = py - qy, dz = pz - qz;
        const float d0 = __builtin_amdgcn_sqrtf((dx * dx + dy * dy) + dz * dz);

        float du = 0.0f, dv = 0.0f, dd = d0;
        float mAu = 0.0f, mAv = 0.0f, mAd = 0.0f;
        float vAu = 0.0f, vAv = 0.0f, vAd = 0.0f;

#pragma unroll
        for (int it = 0; it < kInner; ++it) {
            const float bu = vwu + du;
            const float bv = vwv + dv;
            const float bw = (1.0f - bu) - bv;

            const float cVx = ((bu * V0x + bv * V1x) + bw * V2x) * SCALE;
            const float cVy = ((bu * V0y + bv * V1y) + bw * V2y) * SCALE;
            const float cVz = ((bu * V0z + bv * V1z) + bw * V2z) * SCALE;

            const float nrx = (bu * N0x + bv * N1x) + bw * N2x;
            const float nry = (bu * N0y + bv * N1y) + bw * N2y;
            const float nrz = (bu * N0z + bv * N1z) + bw * N2z;
            const float nn  = (nrx * nrx + nry * nry) + nrz * nrz;
            // 1/max(sqrt(nn),1e-12) == rsq(nn) for the magnitudes here
            const float inv = __builtin_amdgcn_rsqf(nn);
            const float nhx = nrx * inv, nhy = nry * inv, nhz = nrz * inv;
            const float cNx = nhx * SCALE, cNy = nhy * SCALE, cNz = nhz * SCALE;

            const float rx = (cVx + cNx * dd) - tx;
            const float ry = (cVy + cNy * dd) - ty;
            const float rz = (cVz + cNz * dd) - tz;

            const float rv0  = (rx * E0x + ry * E0y) + rz * E0z;
            const float rv1  = (rx * E1x + ry * E1y) + rz * E1z;
            const float rn0  = (rx * F0x + ry * F0y) + rz * F0z;
            const float rn1  = (rx * F1x + ry * F1y) + rz * F1z;
            const float nf0  = (nhx * F0x + nhy * F0y) + nhz * F0z;
            const float nf1  = (nhx * F1x + nhy * F1y) + nhz * F1z;
            const float nr_r = (nhx * rx + nhy * ry) + nhz * rz;

            const float gu = GS * (SCALE * rv0 + (dd * SCALE) * ((rn0 - nr_r * nf0) * inv));
            const float gv = GS * (SCALE * rv1 + (dd * SCALE) * ((rn1 - nr_r * nf1) * inv));
            const float gd = GS * (SCALE * nr_r);

            mAu = B1 * mAu + ONE_M_B1 * gu;
            mAv = B1 * mAv + ONE_M_B1 * gv;
            mAd = B1 * mAd + ONE_M_B1 * gd;
            vAu = B2 * vAu + ONE_M_B2 * (gu * gu);
            vAv = B2 * vAv + ONE_M_B2 * (gv * gv);
            vAd = B2 * vAd + ONE_M_B2 * (gd * gd);

            const float rb1 = kTab.rb1[it];   // compile-time literal (full unroll)
            const float rb2 = kTab.rb2[it];
            // mhat/(sqrt(vhat)+1e-8) ~= mhat * rsq(vhat + 1e-16)
            const float su = __builtin_amdgcn_rsqf(vAu * rb2 + 1e-16f);
            const float sv = __builtin_amdgcn_rsqf(vAv * rb2 + 1e-16f);
            const float sd = __builtin_amdgcn_rsqf(vAd * rb2 + 1e-16f);
            du -= 0.01f * (mAu * rb1) * su;
            dv -= 0.01f * (mAv * rb1) * sv;
            dd -= 0.01f * (mAd * rb1) * sd;
        }
        vwu += du;
        vwv += dv;
    }

    out[kPts + 2 * p + 0] = vwu;
    out[kPts + 2 * p + 1] = vwv;
    out[3 * kPts + p]     = 0.0f;   // outlier_mask = False
}

extern "C" void kernel_launch(void* const* d_in, const int* in_sizes, int n_in,
                              void* d_out, int out_size, void* d_ws, size_t ws_size,
                              hipStream_t stream) {
    const float* verts  = (const float*)d_in[0];
    const float* mesh_V = (const float*)d_in[1];
    const float* mesh_N = (const float*)d_in[2];
    const int*   mesh_F = (const int*)d_in[3];
    float* out = (float*)d_out;

    // workspace layout: centers | d2 candidates [4][kPts] | face candidates
    float4* ws_cent = (float4*)d_ws;                                        // kFaces float4 (160000 B)
    float*  ws_d2   = (float*)((char*)d_ws + kFaces * sizeof(float4));      // KNN_FQ*kPts floats
    int*    ws_f    = (int*)((char*)ws_d2 + KNN_FQ * kPts * sizeof(float)); // KNN_FQ*kPts ints

    hipLaunchKernelGGL(centers_kernel, dim3((kFaces + 255) / 256), dim3(256), 0, stream,
                       mesh_V, mesh_F, ws_cent);
    hipLaunchKernelGGL(knn_kernel,     dim3(kPtGroups * KNN_FQ), dim3(1024), 0, stream,
                       verts, ws_cent, ws_d2, ws_f);
    hipLaunchKernelGGL(solve_kernel,   dim3(kPts / 64), dim3(64), 0, stream,
                       verts, mesh_V, mesh_N, mesh_F, ws_d2, ws_f, out);
}

// Round 3
// 132.535 us; speedup vs baseline: 1.2794x; 1.0978x over previous
//
#include <hip/hip_runtime.h>
#include <math.h>
#include <stdint.h>

// Problem constants (match reference)
constexpr int kVerts = 5000;
constexpr int kFaces = 10000;
constexpr int kPts   = 16384;   // BATCH * N_PTS = 2 * 8192
constexpr int kOuter = 4;
constexpr int kInner = 50;

#define SCALE 10.0f

// KNN structure: 2 points per lane, 16 waves per block, 4 face quarters.
// Grid = 128 point-groups x 4 quarters = 512 blocks (2 blocks/CU, 32 waves).
#define KNN_WAVES 16
#define KNN_FQ    4
constexpr int kQuarter     = kFaces / KNN_FQ;        // 2500
constexpr int kPtsPerLane  = 2;
constexpr int kPtsPerBlock = 64 * kPtsPerLane;       // 128
constexpr int kPtGroups    = kPts / kPtsPerBlock;    // 128

// ---------------------------------------------------------------------------
// Adam bias-correction table, padded to kInner+2 so a software-pipelined
// prefetch (one s_load_dwordx4 per 2 steps) never reads out of bounds.
// Values are the SAME constexpr sequential products as all prior rounds ->
// solve output bits unchanged.
// ---------------------------------------------------------------------------
struct BiasTabP { float rb[kInner + 2][2]; };
constexpr BiasTabP make_tabp() {
    BiasTabP t{};
    float b1 = 1.0f, b2 = 1.0f;
    for (int i = 0; i < kInner; ++i) {
        b1 *= 0.9f; b2 *= 0.999f;
        t.rb[i][0] = 1.0f / (1.0f - b1);
        t.rb[i][1] = 1.0f / (1.0f - b2);
    }
    t.rb[kInner][0]     = t.rb[kInner - 1][0];
    t.rb[kInner][1]     = t.rb[kInner - 1][1];
    t.rb[kInner + 1][0] = t.rb[kInner - 1][0];
    t.rb[kInner + 1][1] = t.rb[kInner - 1][1];
    return t;
}
constexpr BiasTabP kTabP = make_tabp();

// ---------------------------------------------------------------------------
// Kernel 0: precompute triangle centers once (bit-identical *_rn formula).
// cent[f] = (cx, cy, cz, cc = |c|^2)
// ---------------------------------------------------------------------------
__global__ __launch_bounds__(256)
void centers_kernel(const float* __restrict__ mesh_V,
                    const int*   __restrict__ mesh_F,
                    float4*      __restrict__ cent)
{
    const int f = blockIdx.x * 256 + threadIdx.x;
    if (f >= kFaces) return;
    const int i0 = mesh_F[f * 3 + 0];
    const int i1 = mesh_F[f * 3 + 1];
    const int i2 = mesh_F[f * 3 + 2];
    const float cx = __fdiv_rn(__fadd_rn(__fadd_rn(mesh_V[i0*3+0], mesh_V[i1*3+0]), mesh_V[i2*3+0]), 3.0f);
    const float cy = __fdiv_rn(__fadd_rn(__fadd_rn(mesh_V[i0*3+1], mesh_V[i1*3+1]), mesh_V[i2*3+1]), 3.0f);
    const float cz = __fdiv_rn(__fadd_rn(__fadd_rn(mesh_V[i0*3+2], mesh_V[i1*3+2]), mesh_V[i2*3+2]), 3.0f);
    const float cc = __fadd_rn(__fadd_rn(__fmul_rn(cx, cx), __fmul_rn(cy, cy)),
                               __fmul_rn(cz, cz));
    cent[f] = make_float4(cx, cy, cz, cc);
}

// ---------------------------------------------------------------------------
// Kernel 1: KNN (K=1).
// Round-7 post-mortem: SMEM stream hit the 64-SGPR ceiling (8 dwordx4 in
// flight = 32 data SGPRs) and SMEM's out-of-order returns force full
// lgkmcnt(0) drains per batch; grid of 256 blocks = 1 block/CU capped
// occupancy at 50%. VALU issue-time 37.8us vs 20.8us counted floor.
// Fix: stage each face-quarter in LDS once per block (coalesced per-lane
// float4 loads), scan via ds_read_b128 at wave-uniform address:
//   - same-address LDS access = broadcast, conflict-free
//   - DS ops complete IN-ORDER -> compiler emits partial lgkmcnt(N),
//     pipelined (unlike SMEM's all-or-nothing drain)
//   - face data in VGPRs, SGPR pressure gone
// Grid back to 512 blocks (2/CU, 32 waves/CU). Distance math and all
// merge/tie semantics unchanged (bit-identical argmin).
// LDS pipe check: 2500 b128 reads x ~12cyc = 30K cyc/CU-pass < 50K cyc
// VALU per SIMD -> stays VALU-bound.
// ---------------------------------------------------------------------------
__global__ __launch_bounds__(1024)
void knn_kernel(const float* __restrict__ verts,
                const float4* __restrict__ cent,
                float*        __restrict__ ws_d2,   // [KNN_FQ][kPts]
                int*          __restrict__ ws_f)    // [KNN_FQ][kPts]
{
    __shared__ float4 s_cent[kQuarter];                    // 40000 B
    __shared__ float  s_best [KNN_WAVES * kPtsPerBlock];   //  8192 B
    __shared__ int    s_bestf[KNN_WAVES * kPtsPerBlock];   //  8192 B

    const int tid  = threadIdx.x;
    const int lane = tid & 63;
    const int wv   = __builtin_amdgcn_readfirstlane(tid >> 6);   // 0..15
    const int pg   = blockIdx.x >> 2;   // point group 0..127
    const int fq   = blockIdx.x & 3;    // face quarter 0..3
    const int qbeg = fq * kQuarter;

    // ---- stage this quarter's centroids into LDS (per-lane coalesced) ----
    for (int i = tid; i < kQuarter; i += 1024)
        s_cent[i] = cent[qbeg + i];

    // ---- load this lane's 2 points; doubled coords (exact) + |q|^2 ----
    const int pA = pg * kPtsPerBlock + lane;
    const int pB = pA + 64;
    const float qxA = verts[pA * 3 + 0], qyA = verts[pA * 3 + 1], qzA = verts[pA * 3 + 2];
    const float qxB = verts[pB * 3 + 0], qyB = verts[pB * 3 + 1], qzB = verts[pB * 3 + 2];
    const float q2A = __fadd_rn(__fadd_rn(__fmul_rn(qxA, qxA), __fmul_rn(qyA, qyA)),
                                __fmul_rn(qzA, qzA));
    const float q2B = __fadd_rn(__fadd_rn(__fmul_rn(qxB, qxB), __fmul_rn(qyB, qyB)),
                                __fmul_rn(qzB, qzB));
    const float dqxA = __fmul_rn(2.0f, qxA), dqyA = __fmul_rn(2.0f, qyA), dqzA = __fmul_rn(2.0f, qzA);
    const float dqxB = __fmul_rn(2.0f, qxB), dqyB = __fmul_rn(2.0f, qyB), dqzB = __fmul_rn(2.0f, qzB);

    __syncthreads();

    // this wave's contiguous local face slice (ascending in wv)
    const int fbeg = (wv * kQuarter) / KNN_WAVES;
    const int fend = ((wv + 1) * kQuarter) / KNN_WAVES;

    // 2 accumulators per point to break the cmp/cndmask dependency chain
    float bdA0 = INFINITY, bdA1 = INFINITY, bdB0 = INFINITY, bdB1 = INFINITY;
    int   bfA0 = 0x7fffffff, bfA1 = 0x7fffffff, bfB0 = 0x7fffffff, bfB1 = 0x7fffffff;

    // d2 = (q2 + |c|^2) - (2qx*cx + 2qy*cy + 2qz*cz)   [bit-identical]
#define KNN_EVAL(FF, C, DQX, DQY, DQZ, Q2, BD, BF)                                    \
    {                                                                                 \
        const float dot2 = __fadd_rn(__fadd_rn(__fmul_rn((DQX), (C).x),               \
                                               __fmul_rn((DQY), (C).y)),              \
                                     __fmul_rn((DQZ), (C).z));                        \
        const float d2 = __fsub_rn(__fadd_rn((Q2), (C).w), dot2);                     \
        if (d2 < (BD)) { (BD) = d2; (BF) = (FF); }                                    \
    }

    int f = fbeg;
#pragma unroll 1
    for (; f + 8 <= fend; f += 8) {
        // wave-uniform LDS addresses -> broadcast ds_read_b128, in-order
        const float4 c0 = s_cent[f + 0];
        const float4 c1 = s_cent[f + 1];
        const float4 c2 = s_cent[f + 2];
        const float4 c3 = s_cent[f + 3];
        const float4 c4 = s_cent[f + 4];
        const float4 c5 = s_cent[f + 5];
        const float4 c6 = s_cent[f + 6];
        const float4 c7 = s_cent[f + 7];
        KNN_EVAL(qbeg + f + 0, c0, dqxA, dqyA, dqzA, q2A, bdA0, bfA0);
        KNN_EVAL(qbeg + f + 1, c1, dqxA, dqyA, dqzA, q2A, bdA1, bfA1);
        KNN_EVAL(qbeg + f + 2, c2, dqxA, dqyA, dqzA, q2A, bdA0, bfA0);
        KNN_EVAL(qbeg + f + 3, c3, dqxA, dqyA, dqzA, q2A, bdA1, bfA1);
        KNN_EVAL(qbeg + f + 4, c4, dqxA, dqyA, dqzA, q2A, bdA0, bfA0);
        KNN_EVAL(qbeg + f + 5, c5, dqxA, dqyA, dqzA, q2A, bdA1, bfA1);
        KNN_EVAL(qbeg + f + 6, c6, dqxA, dqyA, dqzA, q2A, bdA0, bfA0);
        KNN_EVAL(qbeg + f + 7, c7, dqxA, dqyA, dqzA, q2A, bdA1, bfA1);
        KNN_EVAL(qbeg + f + 0, c0, dqxB, dqyB, dqzB, q2B, bdB0, bfB0);
        KNN_EVAL(qbeg + f + 1, c1, dqxB, dqyB, dqzB, q2B, bdB1, bfB1);
        KNN_EVAL(qbeg + f + 2, c2, dqxB, dqyB, dqzB, q2B, bdB0, bfB0);
        KNN_EVAL(qbeg + f + 3, c3, dqxB, dqyB, dqzB, q2B, bdB1, bfB1);
        KNN_EVAL(qbeg + f + 4, c4, dqxB, dqyB, dqzB, q2B, bdB0, bfB0);
        KNN_EVAL(qbeg + f + 5, c5, dqxB, dqyB, dqzB, q2B, bdB1, bfB1);
        KNN_EVAL(qbeg + f + 6, c6, dqxB, dqyB, dqzB, q2B, bdB0, bfB0);
        KNN_EVAL(qbeg + f + 7, c7, dqxB, dqyB, dqzB, q2B, bdB1, bfB1);
    }
    for (; f < fend; ++f) {
        const float4 c0 = s_cent[f];
        KNN_EVAL(qbeg + f, c0, dqxA, dqyA, dqzA, q2A, bdA0, bfA0);  // tail > all acc0 faces
        KNN_EVAL(qbeg + f, c0, dqxB, dqyB, dqzB, q2B, bdB0, bfB0);
    }
#undef KNN_EVAL

    // per-point lexicographic merge of the 2 accumulators (smaller f on ties)
    if (bdA1 < bdA0 || (bdA1 == bdA0 && bfA1 < bfA0)) { bdA0 = bdA1; bfA0 = bfA1; }
    if (bdB1 < bdB0 || (bdB1 == bdB0 && bfB1 < bfB0)) { bdB0 = bdB1; bfB0 = bfB1; }

    __syncthreads();   // all waves done reading s_cent before merge overlaps? (separate arrays; barrier orders the phases)

    s_best [wv * kPtsPerBlock + lane]      = bdA0;
    s_bestf[wv * kPtsPerBlock + lane]      = bfA0;
    s_best [wv * kPtsPerBlock + 64 + lane] = bdB0;
    s_bestf[wv * kPtsPerBlock + 64 + lane] = bfB0;
    __syncthreads();

    // cross-wave merge: wave w's face range strictly below wave w+1's,
    // so strict < keeps the smaller face index on exact ties.
    if (tid < kPtsPerBlock) {
        float best  = s_best[tid];
        int   bestf = s_bestf[tid];
#pragma unroll
        for (int w = 1; w < KNN_WAVES; ++w) {
            const float ob = s_best [w * kPtsPerBlock + tid];
            const int   of = s_bestf[w * kPtsPerBlock + tid];
            if (ob < best) { best = ob; bestf = of; }
        }
        const int p = pg * kPtsPerBlock + tid;
        ws_d2[fq * kPts + p] = best;
        ws_f [fq * kPts + p] = bestf;
    }
}

// ---------------------------------------------------------------------------
// Kernel 2: solve — SAME MATH, SAME CONSTANTS (output bits unchanged).
// Round-7 theory: 200x full unroll = ~12K insts ~ 96KB code vs 32KB L1I,
// at 1 wave/SIMD there is nothing to hide I-fetch misses behind. Change to
// a 25-trip loop of 2 unrolled steps (~1KB body, I$-resident) with the
// bias pair for the NEXT 2 steps prefetched via one s_load_dwordx4 issued
// BEFORE the current 2 steps (~260 cyc of compute hides SMEM latency —
// this is what the old round-3/4 dynamic-index version lacked).
// ---------------------------------------------------------------------------
__global__ __launch_bounds__(64)
void solve_kernel(const float* __restrict__ verts,
                  const float* __restrict__ mesh_V,
                  const float* __restrict__ mesh_N,
                  const int*   __restrict__ mesh_F,
                  const float* __restrict__ ws_d2,
                  const int*   __restrict__ ws_f,
                  float*       __restrict__ out)
{
    const int p = blockIdx.x * 64 + threadIdx.x;

    float bdm = ws_d2[p];
    int   f   = ws_f[p];
#pragma unroll
    for (int q = 1; q < KNN_FQ; ++q) {
        const float d  = ws_d2[q * kPts + p];
        const int   ff = ws_f [q * kPts + p];
        if (d < bdm) { bdm = d; f = ff; }
    }
    out[p] = (float)f;   // fidx as float (exact for idx < 2^24)

    const float qx = verts[p * 3 + 0];
    const float qy = verts[p * 3 + 1];
    const float qz = verts[p * 3 + 2];

    const int i0 = mesh_F[f * 3 + 0];
    const int i1 = mesh_F[f * 3 + 1];
    const int i2 = mesh_F[f * 3 + 2];

    const float V0x = mesh_V[i0*3+0], V0y = mesh_V[i0*3+1], V0z = mesh_V[i0*3+2];
    const float V1x = mesh_V[i1*3+0], V1y = mesh_V[i1*3+1], V1z = mesh_V[i1*3+2];
    const float V2x = mesh_V[i2*3+0], V2y = mesh_V[i2*3+1], V2z = mesh_V[i2*3+2];
    const float N0x = mesh_N[i0*3+0], N0y = mesh_N[i0*3+1], N0z = mesh_N[i0*3+2];
    const float N1x = mesh_N[i1*3+0], N1y = mesh_N[i1*3+1], N1z = mesh_N[i1*3+2];
    const float N2x = mesh_N[i2*3+0], N2y = mesh_N[i2*3+1], N2z = mesh_N[i2*3+2];

    // edge vectors for gradient dots
    const float E0x = V0x - V2x, E0y = V0y - V2y, E0z = V0z - V2z;
    const float E1x = V1x - V2x, E1y = V1y - V2y, E1z = V1z - V2z;
    const float F0x = N0x - N2x, F0y = N0y - N2y, F0z = N0z - N2z;
    const float F1x = N1x - N2x, F1y = N1y - N2y, F1z = N1z - N2z;

    const float tx = qx * SCALE, ty = qy * SCALE, tz = qz * SCALE;
    const float GS = 2.0f / (3.0f * 16384.0f);
    const float B1 = 0.9f,  ONE_M_B1 = 1.0f - 0.9f;
    const float B2 = 0.999f, ONE_M_B2 = 1.0f - 0.999f;

    float vwu = 1.0f / 3.0f, vwv = 1.0f / 3.0f;

    // one Adam step; math/order identical to all prior rounds
#define SOLVE_STEP(RB1, RB2)                                                   \
    {                                                                          \
        const float bu = vwu + du;                                             \
        const float bv = vwv + dv;                                             \
        const float bw = (1.0f - bu) - bv;                                     \
        const float cVx = ((bu * V0x + bv * V1x) + bw * V2x) * SCALE;          \
        const float cVy = ((bu * V0y + bv * V1y) + bw * V2y) * SCALE;          \
        const float cVz = ((bu * V0z + bv * V1z) + bw * V2z) * SCALE;          \
        const float nrx = (bu * N0x + bv * N1x) + bw * N2x;                    \
        const float nry = (bu * N0y + bv * N1y) + bw * N2y;                    \
        const float nrz = (bu * N0z + bv * N1z) + bw * N2z;                    \
        const float nn  = (nrx * nrx + nry * nry) + nrz * nrz;                 \
        const float inv = __builtin_amdgcn_rsqf(nn);                           \
        const float nhx = nrx * inv, nhy = nry * inv, nhz = nrz * inv;         \
        const float cNx = nhx * SCALE, cNy = nhy * SCALE, cNz = nhz * SCALE;   \
        const float rx = (cVx + cNx * dd) - tx;                                \
        const float ry = (cVy + cNy * dd) - ty;                                \
        const float rz = (cVz + cNz * dd) - tz;                                \
        const float rv0  = (rx * E0x + ry * E0y) + rz * E0z;                   \
        const float rv1  = (rx * E1x + ry * E1y) + rz * E1z;                   \
        const float rn0  = (rx * F0x + ry * F0y) + rz * F0z;                   \
        const float rn1  = (rx * F1x + ry * F1y) + rz * F1z;                   \
        const float nf0  = (nhx * F0x + nhy * F0y) + nhz * F0z;                \
        const float nf1  = (nhx * F1x + nhy * F1y) + nhz * F1z;                \
        const float nr_r = (nhx * rx + nhy * ry) + nhz * rz;                   \
        const float gu = GS * (SCALE * rv0 + (dd * SCALE) * ((rn0 - nr_r * nf0) * inv)); \
        const float gv = GS * (SCALE * rv1 + (dd * SCALE) * ((rn1 - nr_r * nf1) * inv)); \
        const float gd = GS * (SCALE * nr_r);                                  \
        mAu = B1 * mAu + ONE_M_B1 * gu;                                        \
        mAv = B1 * mAv + ONE_M_B1 * gv;                                        \
        mAd = B1 * mAd + ONE_M_B1 * gd;                                        \
        vAu = B2 * vAu + ONE_M_B2 * (gu * gu);                                 \
        vAv = B2 * vAv + ONE_M_B2 * (gv * gv);                                 \
        vAd = B2 * vAd + ONE_M_B2 * (gd * gd);                                 \
        const float su = __builtin_amdgcn_rsqf(vAu * (RB2) + 1e-16f);          \
        const float sv = __builtin_amdgcn_rsqf(vAv * (RB2) + 1e-16f);          \
        const float sd = __builtin_amdgcn_rsqf(vAd * (RB2) + 1e-16f);          \
        du -= 0.01f * (mAu * (RB1)) * su;                                      \
        dv -= 0.01f * (mAv * (RB1)) * sv;                                      \
        dd -= 0.01f * (mAd * (RB1)) * sd;                                      \
    }

    for (int outer = 0; outer < kOuter; ++outer) {
        const float bw0 = (1.0f - vwu) - vwv;
        const float px = ((vwu * V0x + vwv * V1x) + bw0 * V2x);
        const float py = ((vwu * V0y + vwv * V1y) + bw0 * V2y);
        const float pz = ((vwu * V0z + vwv * V1z) + bw0 * V2z);
        const float dx = px - qx, dy = py - qy, dz = pz - qz;
        const float d0 = __builtin_amdgcn_sqrtf((dx * dx + dy * dy) + dz * dz);

        float du = 0.0f, dv = 0.0f, dd = d0;
        float mAu = 0.0f, mAv = 0.0f, mAd = 0.0f;
        float vAu = 0.0f, vAv = 0.0f, vAd = 0.0f;

        // software-pipelined bias constants: current pair in registers,
        // next pair prefetched (one s_load_dwordx4) before the 2 steps.
        float rbA1 = kTabP.rb[0][0], rbA2 = kTabP.rb[0][1];
        float rbB1 = kTabP.rb[1][0], rbB2 = kTabP.rb[1][1];
#pragma unroll 1
        for (int i2 = 0; i2 < kInner / 2; ++i2) {
            const float n1a = kTabP.rb[2 * i2 + 2][0];
            const float n2a = kTabP.rb[2 * i2 + 2][1];
            const float n1b = kTabP.rb[2 * i2 + 3][0];
            const float n2b = kTabP.rb[2 * i2 + 3][1];
            SOLVE_STEP(rbA1, rbA2);
            SOLVE_STEP(rbB1, rbB2);
            rbA1 = n1a; rbA2 = n2a; rbB1 = n1b; rbB2 = n2b;
        }
        vwu += du;
        vwv += dv;
    }
#undef SOLVE_STEP

    out[kPts + 2 * p + 0] = vwu;
    out[kPts + 2 * p + 1] = vwv;
    out[3 * kPts + p]     = 0.0f;   // outlier_mask = False
}

extern "C" void kernel_launch(void* const* d_in, const int* in_sizes, int n_in,
                              void* d_out, int out_size, void* d_ws, size_t ws_size,
                              hipStream_t stream) {
    const float* verts  = (const float*)d_in[0];
    const float* mesh_V = (const float*)d_in[1];
    const float* mesh_N = (const float*)d_in[2];
    const int*   mesh_F = (const int*)d_in[3];
    float* out = (float*)d_out;

    // workspace layout: centers | d2 candidates [4][kPts] | face candidates
    float4* ws_cent = (float4*)d_ws;                                        // kFaces float4 (160000 B)
    float*  ws_d2   = (float*)((char*)d_ws + kFaces * sizeof(float4));      // KNN_FQ*kPts floats
    int*    ws_f    = (int*)((char*)ws_d2 + KNN_FQ * kPts * sizeof(float)); // KNN_FQ*kPts ints

    hipLaunchKernelGGL(centers_kernel, dim3((kFaces + 255) / 256), dim3(256), 0, stream,
                       mesh_V, mesh_F, ws_cent);
    hipLaunchKernelGGL(knn_kernel,     dim3(kPtGroups * KNN_FQ), dim3(1024), 0, stream,
                       verts, ws_cent, ws_d2, ws_f);
    hipLaunchKernelGGL(solve_kernel,   dim3(kPts / 64), dim3(64), 0, stream,
                       verts, mesh_V, mesh_N, mesh_F, ws_d2, ws_f, out);
}

// Round 4
// 122.802 us; speedup vs baseline: 1.3808x; 1.0793x over previous
//
#include <hip/hip_runtime.h>
#include <math.h>
#include <stdint.h>

// Problem constants (match reference)
constexpr int kVerts = 5000;
constexpr int kFaces = 10000;
constexpr int kPts   = 16384;   // BATCH * N_PTS = 2 * 8192
constexpr int kOuter = 4;
constexpr int kInner = 50;

#define SCALE 10.0f

// KNN structure: 2 points per lane, 16 waves per block, 4 face quarters.
// Grid = 128 point-groups x 4 quarters = 512 blocks (2 blocks/CU, 32 waves).
#define KNN_WAVES 16
#define KNN_FQ    4
constexpr int kQuarter     = kFaces / KNN_FQ;        // 2500
constexpr int kPtsPerLane  = 2;
constexpr int kPtsPerBlock = 64 * kPtsPerLane;       // 128
constexpr int kPtGroups    = kPts / kPtsPerBlock;    // 128

// ---------------------------------------------------------------------------
// Adam bias-correction table, padded (same constexpr values as all prior
// rounds -> same constants feed the same math).
// ---------------------------------------------------------------------------
struct BiasTabP { float rb[kInner + 2][2]; };
constexpr BiasTabP make_tabp() {
    BiasTabP t{};
    float b1 = 1.0f, b2 = 1.0f;
    for (int i = 0; i < kInner; ++i) {
        b1 *= 0.9f; b2 *= 0.999f;
        t.rb[i][0] = 1.0f / (1.0f - b1);
        t.rb[i][1] = 1.0f / (1.0f - b2);
    }
    t.rb[kInner][0]     = t.rb[kInner - 1][0];
    t.rb[kInner][1]     = t.rb[kInner - 1][1];
    t.rb[kInner + 1][0] = t.rb[kInner - 1][0];
    t.rb[kInner + 1][1] = t.rb[kInner - 1][1];
    return t;
}
constexpr BiasTabP kTabP = make_tabp();

// ---------------------------------------------------------------------------
// Kernel 0: precompute triangle centers once (bit-identical *_rn formula).
// ---------------------------------------------------------------------------
__global__ __launch_bounds__(256)
void centers_kernel(const float* __restrict__ mesh_V,
                    const int*   __restrict__ mesh_F,
                    float4*      __restrict__ cent)
{
    const int f = blockIdx.x * 256 + threadIdx.x;
    if (f >= kFaces) return;
    const int i0 = mesh_F[f * 3 + 0];
    const int i1 = mesh_F[f * 3 + 1];
    const int i2 = mesh_F[f * 3 + 2];
    const float cx = __fdiv_rn(__fadd_rn(__fadd_rn(mesh_V[i0*3+0], mesh_V[i1*3+0]), mesh_V[i2*3+0]), 3.0f);
    const float cy = __fdiv_rn(__fadd_rn(__fadd_rn(mesh_V[i0*3+1], mesh_V[i1*3+1]), mesh_V[i2*3+1]), 3.0f);
    const float cz = __fdiv_rn(__fadd_rn(__fadd_rn(mesh_V[i0*3+2], mesh_V[i1*3+2]), mesh_V[i2*3+2]), 3.0f);
    const float cc = __fadd_rn(__fadd_rn(__fmul_rn(cx, cx), __fmul_rn(cy, cy)),
                               __fmul_rn(cz, cz));
    cent[f] = make_float4(cx, cy, cz, cc);
}

// ---------------------------------------------------------------------------
// Kernel 1: KNN (K=1). UNCHANGED from round 3 (LDS broadcast scan fixed the
// SMEM-drain stall; knn dropped below solve in the profile).
// ---------------------------------------------------------------------------
__global__ __launch_bounds__(1024)
void knn_kernel(const float* __restrict__ verts,
                const float4* __restrict__ cent,
                float*        __restrict__ ws_d2,   // [KNN_FQ][kPts]
                int*          __restrict__ ws_f)    // [KNN_FQ][kPts]
{
    __shared__ float4 s_cent[kQuarter];                    // 40000 B
    __shared__ float  s_best [KNN_WAVES * kPtsPerBlock];   //  8192 B
    __shared__ int    s_bestf[KNN_WAVES * kPtsPerBlock];   //  8192 B

    const int tid  = threadIdx.x;
    const int lane = tid & 63;
    const int wv   = __builtin_amdgcn_readfirstlane(tid >> 6);   // 0..15
    const int pg   = blockIdx.x >> 2;   // point group 0..127
    const int fq   = blockIdx.x & 3;    // face quarter 0..3
    const int qbeg = fq * kQuarter;

    // ---- stage this quarter's centroids into LDS (per-lane coalesced) ----
    for (int i = tid; i < kQuarter; i += 1024)
        s_cent[i] = cent[qbeg + i];

    // ---- load this lane's 2 points; doubled coords (exact) + |q|^2 ----
    const int pA = pg * kPtsPerBlock + lane;
    const int pB = pA + 64;
    const float qxA = verts[pA * 3 + 0], qyA = verts[pA * 3 + 1], qzA = verts[pA * 3 + 2];
    const float qxB = verts[pB * 3 + 0], qyB = verts[pB * 3 + 1], qzB = verts[pB * 3 + 2];
    const float q2A = __fadd_rn(__fadd_rn(__fmul_rn(qxA, qxA), __fmul_rn(qyA, qyA)),
                                __fmul_rn(qzA, qzA));
    const float q2B = __fadd_rn(__fadd_rn(__fmul_rn(qxB, qxB), __fmul_rn(qyB, qyB)),
                                __fmul_rn(qzB, qzB));
    const float dqxA = __fmul_rn(2.0f, qxA), dqyA = __fmul_rn(2.0f, qyA), dqzA = __fmul_rn(2.0f, qzA);
    const float dqxB = __fmul_rn(2.0f, qxB), dqyB = __fmul_rn(2.0f, qyB), dqzB = __fmul_rn(2.0f, qzB);

    __syncthreads();

    // this wave's contiguous local face slice (ascending in wv)
    const int fbeg = (wv * kQuarter) / KNN_WAVES;
    const int fend = ((wv + 1) * kQuarter) / KNN_WAVES;

    float bdA0 = INFINITY, bdA1 = INFINITY, bdB0 = INFINITY, bdB1 = INFINITY;
    int   bfA0 = 0x7fffffff, bfA1 = 0x7fffffff, bfB0 = 0x7fffffff, bfB1 = 0x7fffffff;

#define KNN_EVAL(FF, C, DQX, DQY, DQZ, Q2, BD, BF)                                    \
    {                                                                                 \
        const float dot2 = __fadd_rn(__fadd_rn(__fmul_rn((DQX), (C).x),               \
                                               __fmul_rn((DQY), (C).y)),              \
                                     __fmul_rn((DQZ), (C).z));                        \
        const float d2 = __fsub_rn(__fadd_rn((Q2), (C).w), dot2);                     \
        if (d2 < (BD)) { (BD) = d2; (BF) = (FF); }                                    \
    }

    int f = fbeg;
#pragma unroll 1
    for (; f + 8 <= fend; f += 8) {
        const float4 c0 = s_cent[f + 0];
        const float4 c1 = s_cent[f + 1];
        const float4 c2 = s_cent[f + 2];
        const float4 c3 = s_cent[f + 3];
        const float4 c4 = s_cent[f + 4];
        const float4 c5 = s_cent[f + 5];
        const float4 c6 = s_cent[f + 6];
        const float4 c7 = s_cent[f + 7];
        KNN_EVAL(qbeg + f + 0, c0, dqxA, dqyA, dqzA, q2A, bdA0, bfA0);
        KNN_EVAL(qbeg + f + 1, c1, dqxA, dqyA, dqzA, q2A, bdA1, bfA1);
        KNN_EVAL(qbeg + f + 2, c2, dqxA, dqyA, dqzA, q2A, bdA0, bfA0);
        KNN_EVAL(qbeg + f + 3, c3, dqxA, dqyA, dqzA, q2A, bdA1, bfA1);
        KNN_EVAL(qbeg + f + 4, c4, dqxA, dqyA, dqzA, q2A, bdA0, bfA0);
        KNN_EVAL(qbeg + f + 5, c5, dqxA, dqyA, dqzA, q2A, bdA1, bfA1);
        KNN_EVAL(qbeg + f + 6, c6, dqxA, dqyA, dqzA, q2A, bdA0, bfA0);
        KNN_EVAL(qbeg + f + 7, c7, dqxA, dqyA, dqzA, q2A, bdA1, bfA1);
        KNN_EVAL(qbeg + f + 0, c0, dqxB, dqyB, dqzB, q2B, bdB0, bfB0);
        KNN_EVAL(qbeg + f + 1, c1, dqxB, dqyB, dqzB, q2B, bdB1, bfB1);
        KNN_EVAL(qbeg + f + 2, c2, dqxB, dqyB, dqzB, q2B, bdB0, bfB0);
        KNN_EVAL(qbeg + f + 3, c3, dqxB, dqyB, dqzB, q2B, bdB1, bfB1);
        KNN_EVAL(qbeg + f + 4, c4, dqxB, dqyB, dqzB, q2B, bdB0, bfB0);
        KNN_EVAL(qbeg + f + 5, c5, dqxB, dqyB, dqzB, q2B, bdB1, bfB1);
        KNN_EVAL(qbeg + f + 6, c6, dqxB, dqyB, dqzB, q2B, bdB0, bfB0);
        KNN_EVAL(qbeg + f + 7, c7, dqxB, dqyB, dqzB, q2B, bdB1, bfB1);
    }
    for (; f < fend; ++f) {
        const float4 c0 = s_cent[f];
        KNN_EVAL(qbeg + f, c0, dqxA, dqyA, dqzA, q2A, bdA0, bfA0);
        KNN_EVAL(qbeg + f, c0, dqxB, dqyB, dqzB, q2B, bdB0, bfB0);
    }
#undef KNN_EVAL

    if (bdA1 < bdA0 || (bdA1 == bdA0 && bfA1 < bfA0)) { bdA0 = bdA1; bfA0 = bfA1; }
    if (bdB1 < bdB0 || (bdB1 == bdB0 && bfB1 < bfB0)) { bdB0 = bdB1; bfB0 = bfB1; }

    __syncthreads();

    s_best [wv * kPtsPerBlock + lane]      = bdA0;
    s_bestf[wv * kPtsPerBlock + lane]      = bfA0;
    s_best [wv * kPtsPerBlock + 64 + lane] = bdB0;
    s_bestf[wv * kPtsPerBlock + 64 + lane] = bfB0;
    __syncthreads();

    if (tid < kPtsPerBlock) {
        float best  = s_best[tid];
        int   bestf = s_bestf[tid];
#pragma unroll
        for (int w = 1; w < KNN_WAVES; ++w) {
            const float ob = s_best [w * kPtsPerBlock + tid];
            const int   of = s_bestf[w * kPtsPerBlock + tid];
            if (ob < best) { best = ob; bestf = of; }
        }
        const int p = pg * kPtsPerBlock + tid;
        ws_d2[fq * kPts + p] = best;
        ws_f [fq * kPts + p] = bestf;
    }
}

// ---------------------------------------------------------------------------
// quad_perm DPP broadcast: all lanes of each 4-lane quad read lane K of the
// quad. Pure-VALU (v_mov_b32 dpp), exact bit copy, no waitcnt.
// ---------------------------------------------------------------------------
template<int K>
__device__ __forceinline__ float qbcast(float v) {
    return __int_as_float(__builtin_amdgcn_update_dpp(
        0, __float_as_int(v), K * 0x55 /*quad_perm[K,K,K,K]*/, 0xF, 0xF, true));
}

// ---------------------------------------------------------------------------
// Kernel 2: solve.
// Round-8 post-mortem: Occupancy 2.4% / VALUBusy 15.4% -> 256 waves spread
// 1 per CU: 1 of 4 SIMDs active, 768 of 1024 SIMDs idle; per-wave issue
// ~61% of cycles (dep stalls). Waves are capped by points/64 -- unless a
// point spans lanes.
// Fix: 4 lanes per point, one Adam channel per lane (u,v,d,d-dup). The
// channel gradients unify to ONE instruction stream:
//   g = GS*(SCALE*(r.A) + (dd*SCALE)*(((r.B) - nr_r*(nh.B))*inv))
// with (A,B) = (E0,F0) | (E1,F1) | (nh,0). The d case collapses exactly to
// GS*SCALE*nr_r (zero products are exact; +/-0 diffs cannot propagate
// through x -= +/-0). Per-iter cross-lane traffic = 4 quad_perm DPP
// broadcasts (du,dv,dd,nr_r), exact bit copies.
// Waves: 256 -> 1024 (one per SIMD chip-wide); per-lane insts/iter
// ~105 -> ~72; rsq/iter 4 -> 2.
// ---------------------------------------------------------------------------
__global__ __launch_bounds__(256)
void solve_kernel(const float* __restrict__ verts,
                  const float* __restrict__ mesh_V,
                  const float* __restrict__ mesh_N,
                  const int*   __restrict__ mesh_F,
                  const float* __restrict__ ws_d2,
                  const int*   __restrict__ ws_f,
                  float*       __restrict__ out)
{
    const int t  = blockIdx.x * 256 + threadIdx.x;
    const int p  = t >> 2;          // point index
    const int ch = t & 3;           // 0=u, 1=v, 2=d, 3=d-duplicate
    const bool isV = (ch == 1);
    const bool isD = (ch >= 2);

    // merge quarters: strict < keeps the earlier quarter on exact ties
    float bdm = ws_d2[p];
    int   f   = ws_f[p];
#pragma unroll
    for (int q = 1; q < KNN_FQ; ++q) {
        const float d  = ws_d2[q * kPts + p];
        const int   ff = ws_f [q * kPts + p];
        if (d < bdm) { bdm = d; f = ff; }
    }
    if (ch == 0) out[p] = (float)f;   // fidx as float (exact for idx < 2^24)

    const float qx = verts[p * 3 + 0];
    const float qy = verts[p * 3 + 1];
    const float qz = verts[p * 3 + 2];

    const int i0 = mesh_F[f * 3 + 0];
    const int i1 = mesh_F[f * 3 + 1];
    const int i2 = mesh_F[f * 3 + 2];

    const float V0x = mesh_V[i0*3+0], V0y = mesh_V[i0*3+1], V0z = mesh_V[i0*3+2];
    const float V1x = mesh_V[i1*3+0], V1y = mesh_V[i1*3+1], V1z = mesh_V[i1*3+2];
    const float V2x = mesh_V[i2*3+0], V2y = mesh_V[i2*3+1], V2z = mesh_V[i2*3+2];
    const float N0x = mesh_N[i0*3+0], N0y = mesh_N[i0*3+1], N0z = mesh_N[i0*3+2];
    const float N1x = mesh_N[i1*3+0], N1y = mesh_N[i1*3+1], N1z = mesh_N[i1*3+2];
    const float N2x = mesh_N[i2*3+0], N2y = mesh_N[i2*3+1], N2z = mesh_N[i2*3+2];

    // edge vectors (same formulas as before)
    const float E0x = V0x - V2x, E0y = V0y - V2y, E0z = V0z - V2z;
    const float E1x = V1x - V2x, E1y = V1y - V2y, E1z = V1z - V2z;
    const float F0x = N0x - N2x, F0y = N0y - N2y, F0z = N0z - N2z;
    const float F1x = N1x - N2x, F1y = N1y - N2y, F1z = N1z - N2z;

    // per-lane operand selects (loop-invariant parts)
    const float Aux = isV ? E1x : E0x;   // A when !isD (the isD case is nh, per-iter)
    const float Auy = isV ? E1y : E0y;
    const float Auz = isV ? E1z : E0z;
    const float Bx  = isD ? 0.0f : (isV ? F1x : F0x);
    const float By  = isD ? 0.0f : (isV ? F1y : F0y);
    const float Bz  = isD ? 0.0f : (isV ? F1z : F0z);

    const float tx = qx * SCALE, ty = qy * SCALE, tz = qz * SCALE;
    const float GS = 2.0f / (3.0f * 16384.0f);
    const float B1c = 0.9f,  ONE_M_B1 = 1.0f - 0.9f;
    const float B2c = 0.999f, ONE_M_B2 = 1.0f - 0.999f;

    float vwu = 1.0f / 3.0f, vwv = 1.0f / 3.0f;

    // one Adam step for this lane's channel; math order identical per channel
#define SOLVE_STEP(RB1, RB2)                                                   \
    {                                                                          \
        const float du = qbcast<0>(dlt);                                       \
        const float dv = qbcast<1>(dlt);                                       \
        const float dd = qbcast<2>(dlt);                                       \
        const float bu = vwu + du;                                             \
        const float bv = vwv + dv;                                             \
        const float bw = (1.0f - bu) - bv;                                     \
        const float cVx = ((bu * V0x + bv * V1x) + bw * V2x) * SCALE;          \
        const float cVy = ((bu * V0y + bv * V1y) + bw * V2y) * SCALE;          \
        const float cVz = ((bu * V0z + bv * V1z) + bw * V2z) * SCALE;          \
        const float nrx = (bu * N0x + bv * N1x) + bw * N2x;                    \
        const float nry = (bu * N0y + bv * N1y) + bw * N2y;                    \
        const float nrz = (bu * N0z + bv * N1z) + bw * N2z;                    \
        const float nn  = (nrx * nrx + nry * nry) + nrz * nrz;                 \
        const float inv = __builtin_amdgcn_rsqf(nn);                           \
        const float nhx = nrx * inv, nhy = nry * inv, nhz = nrz * inv;         \
        const float cNx = nhx * SCALE, cNy = nhy * SCALE, cNz = nhz * SCALE;   \
        const float rx = (cVx + cNx * dd) - tx;                                \
        const float ry = (cVy + cNy * dd) - ty;                                \
        const float rz = (cVz + cNz * dd) - tz;                                \
        const float Ax = isD ? nhx : Aux;                                      \
        const float Ay = isD ? nhy : Auy;                                      \
        const float Az = isD ? nhz : Auz;                                      \
        const float dotA = (rx * Ax + ry * Ay) + rz * Az;                      \
        const float dotB = (rx * Bx + ry * By) + rz * Bz;                      \
        const float nhB  = (nhx * Bx + nhy * By) + nhz * Bz;                   \
        const float nr_r = qbcast<2>(dotA);                                    \
        const float g = GS * (SCALE * dotA + (dd * SCALE) * ((dotB - nr_r * nhB) * inv)); \
        mA = B1c * mA + ONE_M_B1 * g;                                          \
        vA = B2c * vA + ONE_M_B2 * (g * g);                                    \
        const float s = __builtin_amdgcn_rsqf(vA * (RB2) + 1e-16f);            \
        dlt -= 0.01f * (mA * (RB1)) * s;                                       \
    }

    for (int outer = 0; outer < kOuter; ++outer) {
        const float bw0 = (1.0f - vwu) - vwv;
        const float px = ((vwu * V0x + vwv * V1x) + bw0 * V2x);
        const float py = ((vwu * V0y + vwv * V1y) + bw0 * V2y);
        const float pz = ((vwu * V0z + vwv * V1z) + bw0 * V2z);
        const float dx = px - qx, dy = py - qy, dz = pz - qz;
        const float d0 = __builtin_amdgcn_sqrtf((dx * dx + dy * dy) + dz * dz);

        float dlt = isD ? d0 : 0.0f;   // this lane's channel delta
        float mA  = 0.0f, vA = 0.0f;

        float rbA1 = kTabP.rb[0][0], rbA2 = kTabP.rb[0][1];
        float rbB1 = kTabP.rb[1][0], rbB2 = kTabP.rb[1][1];
#pragma unroll 1
        for (int it2 = 0; it2 < kInner / 2; ++it2) {
            const float n1a = kTabP.rb[2 * it2 + 2][0];
            const float n2a = kTabP.rb[2 * it2 + 2][1];
            const float n1b = kTabP.rb[2 * it2 + 3][0];
            const float n2b = kTabP.rb[2 * it2 + 3][1];
            SOLVE_STEP(rbA1, rbA2);
            SOLVE_STEP(rbB1, rbB2);
            rbA1 = n1a; rbA2 = n2a; rbB1 = n1b; rbB2 = n2b;
        }
        vwu += qbcast<0>(dlt);
        vwv += qbcast<1>(dlt);
    }
#undef SOLVE_STEP

    if (ch == 0) {
        out[kPts + 2 * p + 0] = vwu;
        out[kPts + 2 * p + 1] = vwv;
        out[3 * kPts + p]     = 0.0f;   // outlier_mask = False
    }
}

extern "C" void kernel_launch(void* const* d_in, const int* in_sizes, int n_in,
                              void* d_out, int out_size, void* d_ws, size_t ws_size,
                              hipStream_t stream) {
    const float* verts  = (const float*)d_in[0];
    const float* mesh_V = (const float*)d_in[1];
    const float* mesh_N = (const float*)d_in[2];
    const int*   mesh_F = (const int*)d_in[3];
    float* out = (float*)d_out;

    // workspace layout: centers | d2 candidates [4][kPts] | face candidates
    float4* ws_cent = (float4*)d_ws;                                        // kFaces float4 (160000 B)
    float*  ws_d2   = (float*)((char*)d_ws + kFaces * sizeof(float4));      // KNN_FQ*kPts floats
    int*    ws_f    = (int*)((char*)ws_d2 + KNN_FQ * kPts * sizeof(float)); // KNN_FQ*kPts ints

    hipLaunchKernelGGL(centers_kernel, dim3((kFaces + 255) / 256), dim3(256), 0, stream,
                       mesh_V, mesh_F, ws_cent);
    hipLaunchKernelGGL(knn_kernel,     dim3(kPtGroups * KNN_FQ), dim3(1024), 0, stream,
                       verts, ws_cent, ws_d2, ws_f);
    hipLaunchKernelGGL(solve_kernel,   dim3(kPts * 4 / 256), dim3(256), 0, stream,
                       verts, mesh_V, mesh_N, mesh_F, ws_d2, ws_f, out);
}